// Round 1
// baseline (1631.893 us; speedup 1.0000x reference)
//
#include <hip/hip_runtime.h>

#define HH 80
#define WW 80
#define BB 8
#define CIN 128     // channels of rgb / thermal each
#define C2 256      // concat channels
#define MID 64
#define OFFC 72
#define NG 4        // deform groups
#define CG 32       // CIN / NG

// ---------------- conv1: concat(rgb,thermal) -> 3x3 conv -> relu ----------------
// grid: B*H blocks (one output row each), block 256 threads = 16 ocg(4 oc) x 16 xg(5 x)
__global__ __launch_bounds__(256) void conv1_kernel(
    const float* __restrict__ rgb, const float* __restrict__ thermal,
    const float* __restrict__ w1, const float* __restrict__ b1,
    float* __restrict__ hdn)
{
    const int by = blockIdx.x;
    const int b = by / HH;
    const int y = by - b * HH;
    const int tid = threadIdx.x;
    const int ocg = tid >> 4;      // 0..15 -> oc base ocg*4
    const int xg  = tid & 15;      // 0..15 -> x base xg*5
    const int x0  = xg * 5;

    __shared__ float sin_[16][3][84];   // [ic][row][col], col 0 <-> x=-1, 82 used

    float acc[4][5];
    #pragma unroll
    for (int o = 0; o < 4; ++o)
        #pragma unroll
        for (int xi = 0; xi < 5; ++xi) acc[o][xi] = 0.f;

    for (int cc = 0; cc < C2; cc += 16) {
        __syncthreads();
        for (int e = tid; e < 16 * 3 * 82; e += 256) {
            int ic  = e / 246;
            int rem = e - ic * 246;
            int r   = rem / 82;
            int col = rem - r * 82;
            int gy = y + r - 1;
            int gx = col - 1;
            float v = 0.f;
            if ((unsigned)gy < HH && (unsigned)gx < WW) {
                int c = cc + ic;
                const float* src = (c < CIN) ? rgb : thermal;
                int csrc = (c < CIN) ? c : c - CIN;
                v = src[((b * CIN + csrc) * HH + gy) * WW + gx];
            }
            sin_[ic][r][col] = v;
        }
        __syncthreads();

        for (int ic = 0; ic < 16; ++ic) {
            int gic = cc + ic;
            float wr[4][9];
            #pragma unroll
            for (int o = 0; o < 4; ++o) {
                const float* wp = w1 + ((size_t)(ocg * 4 + o) * C2 + gic) * 9;
                #pragma unroll
                for (int t = 0; t < 9; ++t) wr[o][t] = wp[t];
            }
            #pragma unroll
            for (int r = 0; r < 3; ++r) {
                float v[7];
                #pragma unroll
                for (int j = 0; j < 7; ++j) v[j] = sin_[ic][r][x0 + j];
                #pragma unroll
                for (int kx = 0; kx < 3; ++kx)
                    #pragma unroll
                    for (int xi = 0; xi < 5; ++xi)
                        #pragma unroll
                        for (int o = 0; o < 4; ++o)
                            acc[o][xi] = fmaf(v[xi + kx], wr[o][r * 3 + kx], acc[o][xi]);
            }
        }
    }

    #pragma unroll
    for (int o = 0; o < 4; ++o) {
        int oc = ocg * 4 + o;
        float bias = b1[oc];
        #pragma unroll
        for (int xi = 0; xi < 5; ++xi) {
            float vv = acc[o][xi] + bias;
            hdn[((b * MID + oc) * HH + y) * WW + (x0 + xi)] = vv > 0.f ? vv : 0.f;
        }
    }
}

// ---------------- conv2: hdn -> 3x3 conv -> *scale -> offsets ----------------
// grid: B*H blocks, block 288 = 18 ocg(4 oc => 72) x 16 xg(5 x)
__global__ __launch_bounds__(288) void conv2_kernel(
    const float* __restrict__ hdn, const float* __restrict__ w2,
    const float* __restrict__ b2, const float* __restrict__ scale_p,
    float* __restrict__ offs)
{
    const int by = blockIdx.x;
    const int b = by / HH;
    const int y = by - b * HH;
    const int tid = threadIdx.x;
    const int ocg = tid / 16;      // 0..17
    const int xg  = tid - ocg * 16;
    const int x0  = xg * 5;

    __shared__ float sin_[32][3][84];

    float acc[4][5];
    #pragma unroll
    for (int o = 0; o < 4; ++o)
        #pragma unroll
        for (int xi = 0; xi < 5; ++xi) acc[o][xi] = 0.f;

    const float scale = scale_p[0];

    for (int cc = 0; cc < MID; cc += 32) {
        __syncthreads();
        for (int e = tid; e < 32 * 3 * 82; e += 288) {
            int ic  = e / 246;
            int rem = e - ic * 246;
            int r   = rem / 82;
            int col = rem - r * 82;
            int gy = y + r - 1;
            int gx = col - 1;
            float v = 0.f;
            if ((unsigned)gy < HH && (unsigned)gx < WW)
                v = hdn[((b * MID + cc + ic) * HH + gy) * WW + gx];
            sin_[ic][r][col] = v;
        }
        __syncthreads();

        for (int ic = 0; ic < 32; ++ic) {
            int gic = cc + ic;
            float wr[4][9];
            #pragma unroll
            for (int o = 0; o < 4; ++o) {
                const float* wp = w2 + ((size_t)(ocg * 4 + o) * MID + gic) * 9;
                #pragma unroll
                for (int t = 0; t < 9; ++t) wr[o][t] = wp[t];
            }
            #pragma unroll
            for (int r = 0; r < 3; ++r) {
                float v[7];
                #pragma unroll
                for (int j = 0; j < 7; ++j) v[j] = sin_[ic][r][x0 + j];
                #pragma unroll
                for (int kx = 0; kx < 3; ++kx)
                    #pragma unroll
                    for (int xi = 0; xi < 5; ++xi)
                        #pragma unroll
                        for (int o = 0; o < 4; ++o)
                            acc[o][xi] = fmaf(v[xi + kx], wr[o][r * 3 + kx], acc[o][xi]);
            }
        }
    }

    #pragma unroll
    for (int o = 0; o < 4; ++o) {
        int oc = ocg * 4 + o;
        float bias = b2[oc];
        #pragma unroll
        for (int xi = 0; xi < 5; ++xi) {
            float vv = (acc[o][xi] + bias) * scale;
            offs[((b * OFFC + oc) * HH + y) * WW + (x0 + xi)] = vv;
        }
    }
}

// ---------------- deformable conv 3x3, groups=4 ----------------
// grid: B*H blocks, block 256 = 16 ocg(8 oc => 128) x 16 xg(5 x)
__global__ __launch_bounds__(256) void deform_kernel(
    const float* __restrict__ rgb, const float* __restrict__ offs,
    const float* __restrict__ dw, const float* __restrict__ db,
    float* __restrict__ out)
{
    const int by = blockIdx.x;
    const int b = by / HH;
    const int y = by - b * HH;
    const int tid = threadIdx.x;
    const int ocg = tid >> 4;      // 0..15, 8 oc each
    const int xg  = tid & 15;
    const int x0  = xg * 5;
    const int g   = ocg >> 2;      // deform group (8 oc per ocg, 32 oc per group)

    __shared__ float sw[128 * 33]; // dw[:, :, tap], padded stride to avoid bank conflict

    float acc[8][5];
    #pragma unroll
    for (int o = 0; o < 8; ++o)
        #pragma unroll
        for (int xi = 0; xi < 5; ++xi) acc[o][xi] = 0.f;

    for (int tap = 0; tap < 9; ++tap) {
        __syncthreads();
        for (int e = tid; e < 128 * 32; e += 256) {
            int oc = e >> 5;
            int c  = e & 31;
            sw[oc * 33 + c] = dw[(size_t)e * 9 + tap];
        }
        __syncthreads();

        const int ky = tap / 3 - 1;
        const int kx = tap - (tap / 3) * 3 - 1;

        int   cy[5], cx[5];
        float wy[5], wx[5];
        #pragma unroll
        for (int xi = 0; xi < 5; ++xi) {
            int x = x0 + xi;
            float offy = offs[((b * OFFC + (g * 9 + tap) * 2) * HH + y) * WW + x];
            float offx = offs[((b * OFFC + (g * 9 + tap) * 2 + 1) * HH + y) * WW + x];
            float sy = (float)(y + ky) + offy;
            float sx = (float)(x + kx) + offx;
            float fy = floorf(sy), fx = floorf(sx);
            cy[xi] = (int)fy; cx[xi] = (int)fx;
            wy[xi] = sy - fy; wx[xi] = sx - fx;
        }

        const float* gbase = rgb + ((size_t)b * CIN + g * CG) * HH * WW;
        for (int c = 0; c < CG; ++c) {
            const float* bp = gbase + c * HH * WW;
            float wreg[8];
            #pragma unroll
            for (int o = 0; o < 8; ++o) wreg[o] = sw[(ocg * 8 + o) * 33 + c];
            #pragma unroll
            for (int xi = 0; xi < 5; ++xi) {
                int y0 = cy[xi], xc = cx[xi];
                float w00 = (1.f - wy[xi]) * (1.f - wx[xi]);
                float w01 = (1.f - wy[xi]) * wx[xi];
                float w10 = wy[xi] * (1.f - wx[xi]);
                float w11 = wy[xi] * wx[xi];
                float v = 0.f;
                bool yv0 = (unsigned)y0 < HH;
                bool yv1 = (unsigned)(y0 + 1) < HH;
                bool xv0 = (unsigned)xc < WW;
                bool xv1 = (unsigned)(xc + 1) < WW;
                if (yv0) {
                    const float* rp = bp + y0 * WW;
                    if (xv0) v = fmaf(rp[xc],     w00, v);
                    if (xv1) v = fmaf(rp[xc + 1], w01, v);
                }
                if (yv1) {
                    const float* rp = bp + (y0 + 1) * WW;
                    if (xv0) v = fmaf(rp[xc],     w10, v);
                    if (xv1) v = fmaf(rp[xc + 1], w11, v);
                }
                #pragma unroll
                for (int o = 0; o < 8; ++o)
                    acc[o][xi] = fmaf(v, wreg[o], acc[o][xi]);
            }
        }
    }

    #pragma unroll
    for (int o = 0; o < 8; ++o) {
        int oc = ocg * 8 + o;
        float bias = db[oc];
        #pragma unroll
        for (int xi = 0; xi < 5; ++xi)
            out[((b * CIN + oc) * HH + y) * WW + (x0 + xi)] = acc[o][xi] + bias;
    }
}

extern "C" void kernel_launch(void* const* d_in, const int* in_sizes, int n_in,
                              void* d_out, int out_size, void* d_ws, size_t ws_size,
                              hipStream_t stream) {
    const float* rgb     = (const float*)d_in[0];
    const float* thermal = (const float*)d_in[1];
    const float* w1      = (const float*)d_in[2];
    const float* b1      = (const float*)d_in[3];
    const float* w2      = (const float*)d_in[4];
    const float* b2      = (const float*)d_in[5];
    const float* dw      = (const float*)d_in[6];
    const float* db      = (const float*)d_in[7];
    const float* osc     = (const float*)d_in[8];

    float* hdn  = (float*)d_ws;                                   // 8*64*80*80
    float* offs = hdn + (size_t)BB * MID * HH * WW;               // 8*72*80*80
    float* out  = (float*)d_out;

    dim3 grid(BB * HH);
    conv1_kernel<<<grid, 256, 0, stream>>>(rgb, thermal, w1, b1, hdn);
    conv2_kernel<<<grid, 288, 0, stream>>>(hdn, w2, b2, osc, offs);
    deform_kernel<<<grid, 256, 0, stream>>>(rgb, offs, dw, db, out);
}

// Round 2
// 736.199 us; speedup vs baseline: 2.2166x; 2.2166x over previous
//
#include <hip/hip_runtime.h>

#define HH 80
#define WW 80
#define BB 8
#define CIN 128     // channels of rgb / thermal each
#define C2 256      // concat channels
#define MID 64
#define OFFC 72
#define NG 4        // deform groups
#define CG 32       // CIN / NG
#define HW (HH * WW)

// ---------------- conv1: concat(rgb,thermal) -> 3x3 conv -> relu ----------------
__global__ __launch_bounds__(256) void conv1_kernel(
    const float* __restrict__ rgb, const float* __restrict__ thermal,
    const float* __restrict__ w1, const float* __restrict__ b1,
    float* __restrict__ hdn)
{
    const int by = blockIdx.x;
    const int b = by / HH;
    const int y = by - b * HH;
    const int tid = threadIdx.x;
    const int ocg = tid >> 4;
    const int xg  = tid & 15;
    const int x0  = xg * 5;

    __shared__ float sin_[16][3][84];

    float acc[4][5];
    #pragma unroll
    for (int o = 0; o < 4; ++o)
        #pragma unroll
        for (int xi = 0; xi < 5; ++xi) acc[o][xi] = 0.f;

    for (int cc = 0; cc < C2; cc += 16) {
        __syncthreads();
        for (int e = tid; e < 16 * 3 * 82; e += 256) {
            int ic  = e / 246;
            int rem = e - ic * 246;
            int r   = rem / 82;
            int col = rem - r * 82;
            int gy = y + r - 1;
            int gx = col - 1;
            float v = 0.f;
            if ((unsigned)gy < HH && (unsigned)gx < WW) {
                int c = cc + ic;
                const float* src = (c < CIN) ? rgb : thermal;
                int csrc = (c < CIN) ? c : c - CIN;
                v = src[((b * CIN + csrc) * HH + gy) * WW + gx];
            }
            sin_[ic][r][col] = v;
        }
        __syncthreads();

        for (int ic = 0; ic < 16; ++ic) {
            int gic = cc + ic;
            float wr[4][9];
            #pragma unroll
            for (int o = 0; o < 4; ++o) {
                const float* wp = w1 + ((size_t)(ocg * 4 + o) * C2 + gic) * 9;
                #pragma unroll
                for (int t = 0; t < 9; ++t) wr[o][t] = wp[t];
            }
            #pragma unroll
            for (int r = 0; r < 3; ++r) {
                float v[7];
                #pragma unroll
                for (int j = 0; j < 7; ++j) v[j] = sin_[ic][r][x0 + j];
                #pragma unroll
                for (int kx = 0; kx < 3; ++kx)
                    #pragma unroll
                    for (int xi = 0; xi < 5; ++xi)
                        #pragma unroll
                        for (int o = 0; o < 4; ++o)
                            acc[o][xi] = fmaf(v[xi + kx], wr[o][r * 3 + kx], acc[o][xi]);
            }
        }
    }

    #pragma unroll
    for (int o = 0; o < 4; ++o) {
        int oc = ocg * 4 + o;
        float bias = b1[oc];
        #pragma unroll
        for (int xi = 0; xi < 5; ++xi) {
            float vv = acc[o][xi] + bias;
            hdn[((b * MID + oc) * HH + y) * WW + (x0 + xi)] = vv > 0.f ? vv : 0.f;
        }
    }
}

// ---------------- conv2: hdn -> 3x3 conv -> *scale -> offsets ----------------
__global__ __launch_bounds__(288) void conv2_kernel(
    const float* __restrict__ hdn, const float* __restrict__ w2,
    const float* __restrict__ b2, const float* __restrict__ scale_p,
    float* __restrict__ offs)
{
    const int by = blockIdx.x;
    const int b = by / HH;
    const int y = by - b * HH;
    const int tid = threadIdx.x;
    const int ocg = tid / 16;
    const int xg  = tid - ocg * 16;
    const int x0  = xg * 5;

    __shared__ float sin_[32][3][84];

    float acc[4][5];
    #pragma unroll
    for (int o = 0; o < 4; ++o)
        #pragma unroll
        for (int xi = 0; xi < 5; ++xi) acc[o][xi] = 0.f;

    const float scale = scale_p[0];

    for (int cc = 0; cc < MID; cc += 32) {
        __syncthreads();
        for (int e = tid; e < 32 * 3 * 82; e += 288) {
            int ic  = e / 246;
            int rem = e - ic * 246;
            int r   = rem / 82;
            int col = rem - r * 82;
            int gy = y + r - 1;
            int gx = col - 1;
            float v = 0.f;
            if ((unsigned)gy < HH && (unsigned)gx < WW)
                v = hdn[((b * MID + cc + ic) * HH + gy) * WW + gx];
            sin_[ic][r][col] = v;
        }
        __syncthreads();

        for (int ic = 0; ic < 32; ++ic) {
            int gic = cc + ic;
            float wr[4][9];
            #pragma unroll
            for (int o = 0; o < 4; ++o) {
                const float* wp = w2 + ((size_t)(ocg * 4 + o) * MID + gic) * 9;
                #pragma unroll
                for (int t = 0; t < 9; ++t) wr[o][t] = wp[t];
            }
            #pragma unroll
            for (int r = 0; r < 3; ++r) {
                float v[7];
                #pragma unroll
                for (int j = 0; j < 7; ++j) v[j] = sin_[ic][r][x0 + j];
                #pragma unroll
                for (int kx = 0; kx < 3; ++kx)
                    #pragma unroll
                    for (int xi = 0; xi < 5; ++xi)
                        #pragma unroll
                        for (int o = 0; o < 4; ++o)
                            acc[o][xi] = fmaf(v[xi + kx], wr[o][r * 3 + kx], acc[o][xi]);
            }
        }
    }

    #pragma unroll
    for (int o = 0; o < 4; ++o) {
        int oc = ocg * 4 + o;
        float bias = b2[oc];
        #pragma unroll
        for (int xi = 0; xi < 5; ++xi) {
            float vv = (acc[o][xi] + bias) * scale;
            offs[((b * OFFC + oc) * HH + y) * WW + (x0 + xi)] = vv;
        }
    }
}

// ---------------- transpose rgb NCHW -> NHWC ----------------
// grid: B*H*(C/32), block 256
__global__ __launch_bounds__(256) void transpose_rgb_kernel(
    const float* __restrict__ rgb, float* __restrict__ rgbT)
{
    const int bid = blockIdx.x;
    const int ct = bid & 3;           // C/32 = 4 tiles
    const int rem = bid >> 2;
    const int y = rem % HH;
    const int b = rem / HH;

    __shared__ float tile[32][81];

    for (int e = threadIdx.x; e < 32 * WW; e += 256) {
        int c = e / WW, x = e - (e / WW) * WW;
        tile[c][x] = rgb[((size_t)(b * CIN + ct * 32 + c) * HH + y) * WW + x];
    }
    __syncthreads();
    for (int e = threadIdx.x; e < 32 * WW; e += 256) {
        int x = e >> 5, c = e & 31;
        rgbT[(((size_t)b * HH + y) * WW + x) * CIN + ct * 32 + c] = tile[c][x];
    }
}

// ---------------- transpose deform weights [g][oc][c][tap] -> [g][tap][c][oc] ----
__global__ __launch_bounds__(256) void transpose_dw_kernel(
    const float* __restrict__ dw, float* __restrict__ dwT)
{
    int idx = blockIdx.x * 256 + threadIdx.x;
    if (idx >= NG * 9 * CG * CG) return;
    int oc  = idx & 31;
    int c   = (idx >> 5) & 31;
    int tap = (idx >> 10) % 9;
    int g   = idx / (9 * 1024);
    dwT[idx] = dw[((size_t)(g * CG + oc) * CG + c) * 9 + tap];
}

// ---------------- deformable conv 3x3, groups=4, NHWC gathers ----------------
// grid: B*NG*25 blocks, 256 threads; thread = one output pixel p, all 32 oc
__global__ __launch_bounds__(256) void deform_kernel(
    const float* __restrict__ rgbT, const float* __restrict__ offs,
    const float* __restrict__ dwT, const float* __restrict__ db,
    float* __restrict__ out)
{
    const int bid = blockIdx.x;
    const int pt  = bid % 25;
    const int rem = bid / 25;
    const int g   = rem & 3;
    const int b   = rem >> 2;
    const int p   = pt * 256 + threadIdx.x;   // 0..6399
    const int y   = p / WW;
    const int x   = p - y * WW;

    float acc[32];
    #pragma unroll
    for (int i = 0; i < 32; ++i) acc[i] = 0.f;

    const float* gb = rgbT + (size_t)b * HW * CIN + g * CG;   // + (y*WW+x)*CIN
    const float* wg = dwT + (size_t)g * 9 * CG * CG;          // [tap][c][oc]
    const float* ob = offs + ((size_t)b * OFFC + g * 18) * HW + p;

    for (int tap = 0; tap < 9; ++tap) {
        const int ky = tap / 3 - 1;
        const int kx = tap - (tap / 3) * 3 - 1;
        float offy = ob[(size_t)(2 * tap) * HW];
        float offx = ob[(size_t)(2 * tap + 1) * HW];
        float sy = (float)(y + ky) + offy;
        float sx = (float)(x + kx) + offx;
        float fy = floorf(sy), fx = floorf(sx);
        int iy = (int)fy, ix = (int)fx;
        float wy = sy - fy, wx = sx - fx;
        float w00 = (1.f - wy) * (1.f - wx);
        float w01 = (1.f - wy) * wx;
        float w10 = wy * (1.f - wx);
        float w11 = wy * wx;

        float samp[32];
        #pragma unroll
        for (int i = 0; i < 32; ++i) samp[i] = 0.f;

        const bool v0 = (unsigned)iy < HH;
        const bool v1 = (unsigned)(iy + 1) < HH;
        const bool u0 = (unsigned)ix < WW;
        const bool u1 = (unsigned)(ix + 1) < WW;
        const float* r00 = gb + ((size_t)iy * WW + ix) * CIN;

        auto addc = [&](const float* base, float wgt) {
            const float4* p4 = reinterpret_cast<const float4*>(base);
            #pragma unroll
            for (int q = 0; q < 8; ++q) {
                float4 v = p4[q];
                samp[4 * q + 0] = fmaf(v.x, wgt, samp[4 * q + 0]);
                samp[4 * q + 1] = fmaf(v.y, wgt, samp[4 * q + 1]);
                samp[4 * q + 2] = fmaf(v.z, wgt, samp[4 * q + 2]);
                samp[4 * q + 3] = fmaf(v.w, wgt, samp[4 * q + 3]);
            }
        };
        if (v0 && u0) addc(r00, w00);
        if (v0 && u1) addc(r00 + CIN, w01);
        if (v1 && u0) addc(r00 + WW * CIN, w10);
        if (v1 && u1) addc(r00 + (WW + 1) * CIN, w11);

        // acc[oc] += samp[c] * w[tap][c][oc]  (uniform weight reads -> SMEM)
        const float* wtap = wg + tap * CG * CG;
        #pragma unroll
        for (int c = 0; c < 32; ++c) {
            float s = samp[c];
            #pragma unroll
            for (int oc = 0; oc < 32; ++oc)
                acc[oc] = fmaf(s, wtap[c * 32 + oc], acc[oc]);
        }
    }

    const size_t obase = ((size_t)b * CIN + g * CG) * HW + p;
    #pragma unroll
    for (int oc = 0; oc < 32; ++oc)
        out[obase + (size_t)oc * HW] = acc[oc] + db[g * CG + oc];
}

extern "C" void kernel_launch(void* const* d_in, const int* in_sizes, int n_in,
                              void* d_out, int out_size, void* d_ws, size_t ws_size,
                              hipStream_t stream) {
    const float* rgb     = (const float*)d_in[0];
    const float* thermal = (const float*)d_in[1];
    const float* w1      = (const float*)d_in[2];
    const float* b1      = (const float*)d_in[3];
    const float* w2      = (const float*)d_in[4];
    const float* b2      = (const float*)d_in[5];
    const float* dw      = (const float*)d_in[6];
    const float* db      = (const float*)d_in[7];
    const float* osc     = (const float*)d_in[8];

    float* hdn  = (float*)d_ws;                                    // 8*64*6400
    float* offs = hdn + (size_t)BB * MID * HW;                     // 8*72*6400
    float* rgbT = offs + (size_t)BB * OFFC * HW;                   // 8*6400*128
    float* dwT  = rgbT + (size_t)BB * HW * CIN;                    // 4*9*32*32
    float* out  = (float*)d_out;

    transpose_rgb_kernel<<<dim3(BB * HH * 4), 256, 0, stream>>>(rgb, rgbT);
    transpose_dw_kernel<<<dim3((NG * 9 * CG * CG + 255) / 256), 256, 0, stream>>>(dw, dwT);
    conv1_kernel<<<dim3(BB * HH), 256, 0, stream>>>(rgb, thermal, w1, b1, hdn);
    conv2_kernel<<<dim3(BB * HH), 288, 0, stream>>>(hdn, w2, b2, osc, offs);
    deform_kernel<<<dim3(BB * NG * 25), 256, 0, stream>>>(rgbT, offs, dwT, db, out);
}

// Round 3
// 309.574 us; speedup vs baseline: 5.2714x; 2.3781x over previous
//
#include <hip/hip_runtime.h>

#define HH 80
#define WW 80
#define BB 8
#define CIN 128
#define C2 256
#define MID 64
#define OFFC 72
#define NG 4
#define CG 32
#define HW (HH * WW)
#define PD 82           // padded spatial dim
#define PP (PD * PD)    // padded pixels per image

typedef short bf16x8 __attribute__((ext_vector_type(8)));
typedef float f32x4  __attribute__((ext_vector_type(4)));

static __device__ __forceinline__ unsigned short f2bf(float f) {
    union { float f; unsigned u; } v; v.f = f;
    unsigned r = v.u + 0x7fffu + ((v.u >> 16) & 1u);   // RNE
    return (unsigned short)(r >> 16);
}

// ---------------- zero the 1-px border of padded bf16 buffers (every call) ----
__global__ __launch_bounds__(256) void zero_borders(
    unsigned short* __restrict__ rgbcp, unsigned short* __restrict__ hdnp)
{
    int idx = blockIdx.x * 256 + threadIdx.x;
    if (idx >= BB * 324) return;
    int b = idx / 324, e = idx - (idx / 324) * 324;
    int y, x;
    if (e < 82)       { y = 0;  x = e; }
    else if (e < 164) { y = 81; x = e - 82; }
    else if (e < 244) { y = e - 164 + 1; x = 0; }
    else              { y = e - 244 + 1; x = 81; }
    size_t pos = (size_t)b * PP + y * PD + x;
    uint4 z = {0, 0, 0, 0};
    uint4* r = (uint4*)(rgbcp + pos * C2);
    #pragma unroll
    for (int i = 0; i < 32; ++i) r[i] = z;
    uint4* h = (uint4*)(hdnp + pos * MID);
    #pragma unroll
    for (int i = 0; i < 8; ++i) h[i] = z;
}

// ---------------- pack concat(rgb,thermal) NCHW fp32 -> padded NHWC bf16 ------
// grid: B*H*8 blocks (8 = 256ch/32), 256 threads
__global__ __launch_bounds__(256) void pack_rgbc(
    const float* __restrict__ rgb, const float* __restrict__ thermal,
    unsigned short* __restrict__ rgbcp)
{
    const int bid = blockIdx.x;
    const int ct  = bid & 7;
    const int rem = bid >> 3;
    const int y = rem % HH, b = rem / HH;
    const float* src = (ct < 4) ? rgb : thermal;
    const int cbase = (ct & 3) * 32;

    __shared__ float tile[32][81];
    for (int e = threadIdx.x; e < 32 * WW; e += 256) {
        int c = e / WW, x = e - c * WW;
        tile[c][x] = src[((size_t)(b * CIN + cbase + c) * HH + y) * WW + x];
    }
    __syncthreads();
    for (int e = threadIdx.x; e < 16 * WW; e += 256) {
        int x = e >> 4, cp = (e & 15) * 2;
        unsigned lo = f2bf(tile[cp][x]);
        unsigned hi = f2bf(tile[cp + 1][x]);
        *(unsigned*)(rgbcp + ((size_t)b * PP + (size_t)(y + 1) * PD + x + 1) * C2 + ct * 32 + cp)
            = lo | (hi << 16);
    }
}

// ---------------- weight packs ----------------
__global__ __launch_bounds__(256) void pack_w1(
    const float* __restrict__ w1, unsigned short* __restrict__ w1T)
{
    int idx = blockIdx.x * 256 + threadIdx.x;      // 9*64*256
    int tap = idx / (MID * C2);
    int rem = idx - tap * (MID * C2);
    int oc = rem / C2, ic = rem - (rem / C2) * C2;
    w1T[idx] = f2bf(w1[((size_t)oc * C2 + ic) * 9 + tap]);
}

__global__ __launch_bounds__(256) void pack_w2(
    const float* __restrict__ w2, unsigned short* __restrict__ w2T)
{
    int idx = blockIdx.x * 256 + threadIdx.x;      // 9*80*64
    int tap = idx / (80 * MID);
    int rem = idx - tap * (80 * MID);
    int oc = rem / MID, ic = rem - (rem / MID) * MID;
    float v = (oc < OFFC) ? w2[((size_t)oc * MID + ic) * 9 + tap] : 0.f;
    w2T[idx] = f2bf(v);
}

__global__ __launch_bounds__(256) void transpose_dw_kernel(
    const float* __restrict__ dw, float* __restrict__ dwT)
{
    int idx = blockIdx.x * 256 + threadIdx.x;
    if (idx >= NG * 9 * CG * CG) return;
    int oc  = idx & 31;
    int c   = (idx >> 5) & 31;
    int tap = (idx >> 10) % 9;
    int g   = idx / (9 * 1024);
    dwT[idx] = dw[((size_t)(g * CG + oc) * CG + c) * 9 + tap];
}

// ---------------- conv1: implicit GEMM, bf16 MFMA, relu, write padded NHWC ----
// grid: B*H, block 256 (4 waves); wave = nf (16 oc), 5 m-frags of 16 px
__global__ __launch_bounds__(256) void conv1_mfma(
    const unsigned short* __restrict__ rgbcp, const unsigned short* __restrict__ w1T,
    const float* __restrict__ b1, unsigned short* __restrict__ hdnp)
{
    const int by = blockIdx.x;
    const int b = by / HH, y = by - b * HH;
    const int tid = threadIdx.x;
    const int nf = tid >> 6;
    const int l = tid & 63, l15 = l & 15, lk = l >> 4;

    f32x4 acc[5];
    #pragma unroll
    for (int i = 0; i < 5; ++i) acc[i] = (f32x4){0.f, 0.f, 0.f, 0.f};

    const unsigned short* abase =
        rgbcp + ((size_t)b * PP + (size_t)(y + 1) * PD + (l15 + 1)) * C2 + lk * 8;
    const unsigned short* bbase = w1T + ((size_t)(nf * 16 + l15)) * C2 + lk * 8;

    for (int tap = 0; tap < 9; ++tap) {
        const int ky = tap / 3 - 1, kx = tap - (tap / 3) * 3 - 1;
        const unsigned short* at = abase + (ky * PD + kx) * C2;
        const unsigned short* bt = bbase + (size_t)tap * MID * C2;
        for (int cb = 0; cb < 8; ++cb) {
            bf16x8 bf = *(const bf16x8*)(bt + cb * 32);
            #pragma unroll
            for (int mf = 0; mf < 5; ++mf) {
                bf16x8 af = *(const bf16x8*)(at + cb * 32 + mf * 16 * C2);
                acc[mf] = __builtin_amdgcn_mfma_f32_16x16x32_bf16(af, bf, acc[mf], 0, 0, 0);
            }
        }
    }

    const int oc = nf * 16 + l15;
    const float bias = b1[oc];
    unsigned short* ob = hdnp + ((size_t)b * PP + (size_t)(y + 1) * PD + 1) * MID + oc;
    #pragma unroll
    for (int mf = 0; mf < 5; ++mf)
        #pragma unroll
        for (int r = 0; r < 4; ++r) {
            float v = acc[mf][r] + bias;
            v = v > 0.f ? v : 0.f;
            ob[(size_t)(mf * 16 + lk * 4 + r) * MID] = f2bf(v);
        }
}

// ---------------- conv2: implicit GEMM, bf16 MFMA, scale, write NCHW fp32 -----
// grid: B*H, block 320 (5 waves); wave = nf (16 oc of 80 padded), 5 m-frags
__global__ __launch_bounds__(320) void conv2_mfma(
    const unsigned short* __restrict__ hdnp, const unsigned short* __restrict__ w2T,
    const float* __restrict__ b2, const float* __restrict__ scale_p,
    float* __restrict__ offs)
{
    const int by = blockIdx.x;
    const int b = by / HH, y = by - b * HH;
    const int tid = threadIdx.x;
    const int nf = tid >> 6;
    const int l = tid & 63, l15 = l & 15, lk = l >> 4;

    f32x4 acc[5];
    #pragma unroll
    for (int i = 0; i < 5; ++i) acc[i] = (f32x4){0.f, 0.f, 0.f, 0.f};

    const unsigned short* abase =
        hdnp + ((size_t)b * PP + (size_t)(y + 1) * PD + (l15 + 1)) * MID + lk * 8;
    const unsigned short* bbase = w2T + ((size_t)(nf * 16 + l15)) * MID + lk * 8;

    for (int tap = 0; tap < 9; ++tap) {
        const int ky = tap / 3 - 1, kx = tap - (tap / 3) * 3 - 1;
        const unsigned short* at = abase + (ky * PD + kx) * MID;
        const unsigned short* bt = bbase + (size_t)tap * 80 * MID;
        #pragma unroll
        for (int cb = 0; cb < 2; ++cb) {
            bf16x8 bf = *(const bf16x8*)(bt + cb * 32);
            #pragma unroll
            for (int mf = 0; mf < 5; ++mf) {
                bf16x8 af = *(const bf16x8*)(at + cb * 32 + mf * 16 * MID);
                acc[mf] = __builtin_amdgcn_mfma_f32_16x16x32_bf16(af, bf, acc[mf], 0, 0, 0);
            }
        }
    }

    const int oc = nf * 16 + l15;
    if (oc < OFFC) {
        const float scale = scale_p[0];
        const float bias = b2[oc];
        float* ob = offs + ((size_t)b * OFFC + oc) * HW + y * WW;
        #pragma unroll
        for (int mf = 0; mf < 5; ++mf) {
            float4 v;
            v.x = (acc[mf][0] + bias) * scale;
            v.y = (acc[mf][1] + bias) * scale;
            v.z = (acc[mf][2] + bias) * scale;
            v.w = (acc[mf][3] + bias) * scale;
            *(float4*)(ob + mf * 16 + lk * 4) = v;
        }
    }
}

// ---------------- deformable conv 3x3, groups=4, bf16 NHWC gathers ----------
__global__ __launch_bounds__(256) void deform_kernel(
    const unsigned short* __restrict__ rgbcp, const float* __restrict__ offs,
    const float* __restrict__ dwT, const float* __restrict__ db,
    float* __restrict__ out)
{
    const int bid = blockIdx.x;
    const int pt  = bid % 25;
    const int rem = bid / 25;
    const int g   = rem & 3;
    const int b   = rem >> 2;
    const int p   = pt * 256 + threadIdx.x;
    const int y   = p / WW;
    const int x   = p - y * WW;

    float acc[32];
    #pragma unroll
    for (int i = 0; i < 32; ++i) acc[i] = 0.f;

    const unsigned short* gb = rgbcp + (size_t)b * PP * C2 + g * CG;
    const float* wg = dwT + (size_t)g * 9 * CG * CG;
    const float* ob = offs + ((size_t)b * OFFC + g * 18) * HW + p;

    for (int tap = 0; tap < 9; ++tap) {
        const int ky = tap / 3 - 1;
        const int kx = tap - (tap / 3) * 3 - 1;
        float offy = ob[(size_t)(2 * tap) * HW];
        float offx = ob[(size_t)(2 * tap + 1) * HW];
        float sy = (float)(y + ky) + offy;
        float sx = (float)(x + kx) + offx;
        float fy = floorf(sy), fx = floorf(sx);
        int iy = (int)fy, ix = (int)fx;
        float wy = sy - fy, wx = sx - fx;
        float w00 = (1.f - wy) * (1.f - wx);
        float w01 = (1.f - wy) * wx;
        float w10 = wy * (1.f - wx);
        float w11 = wy * wx;

        float samp[32];
        #pragma unroll
        for (int i = 0; i < 32; ++i) samp[i] = 0.f;

        const bool v0 = (unsigned)iy < HH;
        const bool v1 = (unsigned)(iy + 1) < HH;
        const bool u0 = (unsigned)ix < WW;
        const bool u1 = (unsigned)(ix + 1) < WW;
        const unsigned short* r00 = gb + ((size_t)(iy + 1) * PD + (ix + 1)) * C2;

        auto addc = [&](const unsigned short* base, float wgt) {
            const unsigned* pw = reinterpret_cast<const unsigned*>(base);
            #pragma unroll
            for (int q = 0; q < 16; ++q) {
                unsigned u = pw[q];
                float f0 = __uint_as_float(u << 16);
                float f1 = __uint_as_float(u & 0xffff0000u);
                samp[2 * q]     = fmaf(f0, wgt, samp[2 * q]);
                samp[2 * q + 1] = fmaf(f1, wgt, samp[2 * q + 1]);
            }
        };
        if (v0 && u0) addc(r00, w00);
        if (v0 && u1) addc(r00 + C2, w01);
        if (v1 && u0) addc(r00 + PD * C2, w10);
        if (v1 && u1) addc(r00 + (PD + 1) * C2, w11);

        const float* wtap = wg + tap * CG * CG;
        #pragma unroll
        for (int c = 0; c < 32; ++c) {
            float s = samp[c];
            #pragma unroll
            for (int oc = 0; oc < 32; ++oc)
                acc[oc] = fmaf(s, wtap[c * 32 + oc], acc[oc]);
        }
    }

    const size_t obase = ((size_t)b * CIN + g * CG) * HW + p;
    #pragma unroll
    for (int oc = 0; oc < 32; ++oc)
        out[obase + (size_t)oc * HW] = acc[oc] + db[g * CG + oc];
}

extern "C" void kernel_launch(void* const* d_in, const int* in_sizes, int n_in,
                              void* d_out, int out_size, void* d_ws, size_t ws_size,
                              hipStream_t stream) {
    const float* rgb     = (const float*)d_in[0];
    const float* thermal = (const float*)d_in[1];
    const float* w1      = (const float*)d_in[2];
    const float* b1      = (const float*)d_in[3];
    const float* w2      = (const float*)d_in[4];
    const float* b2      = (const float*)d_in[5];
    const float* dw      = (const float*)d_in[6];
    const float* db      = (const float*)d_in[7];
    const float* osc     = (const float*)d_in[8];

    char* w = (char*)d_ws;
    unsigned short* rgbcp = (unsigned short*)w;  w += (size_t)BB * PP * C2 * 2;
    unsigned short* hdnp  = (unsigned short*)w;  w += (size_t)BB * PP * MID * 2;
    float*          offs  = (float*)w;           w += (size_t)BB * OFFC * HW * 4;
    unsigned short* w1T   = (unsigned short*)w;  w += (size_t)9 * MID * C2 * 2;
    unsigned short* w2T   = (unsigned short*)w;  w += (size_t)9 * 80 * MID * 2;
    float*          dwT   = (float*)w;           w += (size_t)NG * 9 * CG * CG * 4;
    float* out = (float*)d_out;

    zero_borders<<<dim3((BB * 324 + 255) / 256), 256, 0, stream>>>(rgbcp, hdnp);
    pack_rgbc<<<dim3(BB * HH * 8), 256, 0, stream>>>(rgb, thermal, rgbcp);
    pack_w1<<<dim3(9 * MID * C2 / 256), 256, 0, stream>>>(w1, w1T);
    pack_w2<<<dim3(9 * 80 * MID / 256), 256, 0, stream>>>(w2, w2T);
    transpose_dw_kernel<<<dim3((NG * 9 * CG * CG + 255) / 256), 256, 0, stream>>>(dw, dwT);
    conv1_mfma<<<dim3(BB * HH), 256, 0, stream>>>(rgbcp, w1T, b1, hdnp);
    conv2_mfma<<<dim3(BB * HH), 320, 0, stream>>>(hdnp, w2T, b2, osc, offs);
    deform_kernel<<<dim3(BB * NG * 25), 256, 0, stream>>>(rgbcp, offs, dwT, db, out);
}